// Round 14
// baseline (112.133 us; speedup 1.0000x reference)
//
#include <hip/hip_runtime.h>
#include <math.h>

#define BSZ 4096
#define DIM 256
// 20 * log2(e): rows are pre-scaled by sqrt(20*log2e)/||row|| so the MFMA
// emits u = score*log2e; exp2(u - SC20L2E) == exp(score - 20) exactly.
#define SC20L2E 28.853900817779268f

#if __has_builtin(__builtin_amdgcn_exp2f)
#define EXP2F(x) __builtin_amdgcn_exp2f(x)
#else
#define EXP2F(x) exp2f(x)
#endif

typedef int   intx8    __attribute__((ext_vector_type(8)));
typedef float floatx16 __attribute__((ext_vector_type(16)));

__device__ __forceinline__ void async_cp16(void* lds, const void* g) {
    __builtin_amdgcn_global_load_lds(
        (__attribute__((address_space(1))) unsigned int*)(unsigned long long)g,
        (__attribute__((address_space(3))) unsigned int*)lds,
        16, 0, 0);
}

// One wave per row index: load row r of all 4 matrices once.
// Outputs: fp8 e4m3 rows pre-scaled by sqrt(20*log2e)/||row||, fp32 diagonal
// scores for the 4 pairs; zeroes rowsum/colsum; inits out[0]=40 (const term).
__global__ __launch_bounds__(256)
void prep_kernel(const float* __restrict__ a0, const float* __restrict__ a1,
                 const float* __restrict__ a2, const float* __restrict__ a3,
                 unsigned char* __restrict__ f8, float* __restrict__ diag,
                 float* __restrict__ rowsum, float* __restrict__ colsum,
                 float* __restrict__ out) {
    const float* srcs[4] = {a0, a1, a2, a3};
    int w = threadIdx.x >> 6, lane = threadIdx.x & 63;
    int row = blockIdx.x * 4 + w;

    float4 v[4];
    float red[8];
    #pragma unroll
    for (int m = 0; m < 4; m++) {
        v[m] = ((const float4*)(srcs[m] + (size_t)row * DIM))[lane];
        red[m] = v[m].x * v[m].x + v[m].y * v[m].y + v[m].z * v[m].z + v[m].w * v[m].w;
    }
    // pair dots: (0,1) (0,2) (1,2) (1,3)
    red[4] = v[0].x * v[1].x + v[0].y * v[1].y + v[0].z * v[1].z + v[0].w * v[1].w;
    red[5] = v[0].x * v[2].x + v[0].y * v[2].y + v[0].z * v[2].z + v[0].w * v[2].w;
    red[6] = v[1].x * v[2].x + v[1].y * v[2].y + v[1].z * v[2].z + v[1].w * v[2].w;
    red[7] = v[1].x * v[3].x + v[1].y * v[3].y + v[1].z * v[3].z + v[1].w * v[3].w;

    #pragma unroll
    for (int i = 0; i < 8; i++) {
        #pragma unroll
        for (int s = 32; s; s >>= 1) red[i] += __shfl_xor(red[i], s, 64);
    }

    float rinv[4];
    #pragma unroll
    for (int m = 0; m < 4; m++) rinv[m] = rsqrtf(fmaxf(red[m], 1e-24f));

    const float sq = sqrtf(SC20L2E);
    #pragma unroll
    for (int m = 0; m < 4; m++) {
        float sc = sq * rinv[m];
        int pk = __builtin_amdgcn_cvt_pk_fp8_f32(v[m].x * sc, v[m].y * sc, 0, false);
        pk = __builtin_amdgcn_cvt_pk_fp8_f32(v[m].z * sc, v[m].w * sc, pk, true);
        ((unsigned int*)(f8 + (size_t)m * BSZ * DIM))[row * 64 + lane] = (unsigned int)pk;
    }

    if (lane == 0) {
        diag[0 * BSZ + row] = red[4] * 20.0f * rinv[0] * rinv[1];
        diag[1 * BSZ + row] = red[5] * 20.0f * rinv[0] * rinv[2];
        diag[2 * BSZ + row] = red[6] * 20.0f * rinv[1] * rinv[2];
        diag[3 * BSZ + row] = red[7] * 20.0f * rinv[1] * rinv[3];
    }
    if (blockIdx.x < 64) {
        int idx = blockIdx.x * 256 + threadIdx.x;
        rowsum[idx] = 0.f;
        colsum[idx] = 0.f;
        if (idx == 0) out[0] = 40.0f;   // + 20*4B/(2B) constant term
    }
}

// Minimal-sync variant: 128x128 tile per block (pair = blockIdx.z), FULL-K
// LDS staging (A 32 KB + B 32 KB = 64 KB, 2 blocks/CU) -> exactly ONE
// __syncthreads per block; the K-loop has zero barriers. The pair kernel is
// pinned at ~42-46 us across MFMA-rate x2 / occupancy x2 / bytes x1.8
// variations -- pipes (VALU ~16us, LDS ~17us, MFMA ~6us) serialize with
// ~1.5 blocks/CU resident; this structure removes every sync the source
// level can remove, and __launch_bounds__(256,2) (VGPR cap 256 -- no R7
// spill risk) requests >=2 blocks/CU residency.
// MX-scaled fp8 MFMA 32x32x64 (unit E8M0 scales 0x7F): numerics = plain fp8.
// Full-K 16-chunk XOR swizzle (verified R13): chunk c of row r at byte
// r*256 + (((c^r)&15)<<4); fragment chunk = ks*4 + h*2 + b -> addr =
// Q[t][b] ^ (ks<<6), Q hoisted.
// A/B operand layout (32x32x64): row = lane&31, k = (lane>>5)*32 + byte.
// C/D layout (32x32): col = lane&31, row = (reg&3)+8*(reg>>2)+4*(lane>>5).
// Accumulators init to -SC20L2E so the epilogue is a bare v_exp_f32.
__global__ __launch_bounds__(256, 2)
void pair_scores_kernel(const unsigned char* __restrict__ f8,
                        float* __restrict__ rowsum,
                        float* __restrict__ colsum) {
    const int PX[4] = {0, 0, 1, 1};
    const int PY[4] = {1, 2, 2, 3};
    int p = blockIdx.z;
    const unsigned char* Xb = f8 + (size_t)PX[p] * BSZ * DIM;
    const unsigned char* Yb = f8 + (size_t)PY[p] * BSZ * DIM;
    float* rs = rowsum + p * BSZ;
    float* cs = colsum + p * BSZ;

    __shared__ __align__(16) unsigned char smem[65536];  // A:0..32K, B:32K..64K

    int tid  = threadIdx.x;
    int lane = tid & 63;
    int w    = tid >> 6;
    int wm = w >> 1, wn = w & 1;
    int l5 = lane & 31, h = lane >> 5;
    int bi = blockIdx.x * 128, bj = blockIdx.y * 128;

    // ---- stage BOTH full-K panels; one barrier total ----
    const unsigned char* gA = Xb + (size_t)bi * 256;
    const unsigned char* gB = Yb + (size_t)bj * 256;
    #pragma unroll
    for (int i = 0; i < 8; i++) {
        int sb  = i * 256 + w * 64;          // wave-uniform chunk base
        int s   = sb + lane;
        int row = s >> 4;
        int c   = (s ^ row) & 15;
        unsigned lo = (unsigned)(sb * 16);
        unsigned go = (unsigned)(row * 256 + c * 16);
        async_cp16(smem + lo,          gA + go);
        async_cp16(smem + 32768 + lo,  gB + go);
    }

    // Hoisted fragment bases: Q[t][b] = r*256 + ((((h*2+b)^r)&15)<<4);
    // per-ks address = Q ^ (ks<<6)  (XOR decomposes: ks*4 occupies bits 2..3
    // of the chunk index, h*2+b bits 0..1).
    unsigned QA[2][2], QB[2][2];
    #pragma unroll
    for (int t = 0; t < 2; t++) {
        int ra = wm * 64 + t * 32 + l5;
        int rb = wn * 64 + t * 32 + l5;
        #pragma unroll
        for (int b = 0; b < 2; b++) {
            QA[t][b] = (unsigned)(ra * 256 + ((((h * 2 + b) ^ ra) & 15) << 4));
            QB[t][b] = (unsigned)(32768 + rb * 256 + ((((h * 2 + b) ^ rb) & 15) << 4));
        }
    }

    floatx16 acc[2][2];
    #pragma unroll
    for (int i = 0; i < 2; i++)
        #pragma unroll
        for (int j = 0; j < 2; j++)
            #pragma unroll
            for (int r = 0; r < 16; r++)
                acc[i][j][r] = -SC20L2E;

    __syncthreads();   // the ONLY barrier: staging drained (vmcnt in barrier)

    #pragma unroll 1   // cap fragment liveness (no spill)
    for (int ks = 0; ks < 4; ks++) {
        unsigned kx = (unsigned)(ks << 6);
        union { long long l[4]; intx8 v; } A[2], B[2];
        #pragma unroll
        for (int t = 0; t < 2; t++) {
            unsigned a0 = QA[t][0] ^ kx, a1 = QA[t][1] ^ kx;
            A[t].l[0] = *(const long long*)(smem + a0);
            A[t].l[1] = *(const long long*)(smem + a0 + 8);
            A[t].l[2] = *(const long long*)(smem + a1);
            A[t].l[3] = *(const long long*)(smem + a1 + 8);
            unsigned b0 = QB[t][0] ^ kx, b1 = QB[t][1] ^ kx;
            B[t].l[0] = *(const long long*)(smem + b0);
            B[t].l[1] = *(const long long*)(smem + b0 + 8);
            B[t].l[2] = *(const long long*)(smem + b1);
            B[t].l[3] = *(const long long*)(smem + b1 + 8);
        }
        #pragma unroll
        for (int i = 0; i < 2; i++)
            #pragma unroll
            for (int j = 0; j < 2; j++)
                acc[i][j] = __builtin_amdgcn_mfma_scale_f32_32x32x64_f8f6f4(
                    A[i].v, B[j].v, acc[i][j], 0, 0,
                    0, 0x7F7F7F7F, 0, 0x7F7F7F7F);
    }

    // ---- epilogue: exp2 (raw v_exp_f32), butterfly reductions, atomics ----
    #pragma unroll
    for (int i = 0; i < 2; i++)
        #pragma unroll
        for (int j = 0; j < 2; j++)
            #pragma unroll
            for (int r = 0; r < 16; r++)
                acc[i][j][r] = EXP2F(acc[i][j][r]);

    // Row sums: v[t], t = ti*16 + reg, reduced over the 32 l5-lanes via
    // 5-level value-splitting butterfly; lane l5 ends holding v[l5].
    float v[32];
    #pragma unroll
    for (int t = 0; t < 2; t++)
        #pragma unroll
        for (int r = 0; r < 16; r++)
            v[t * 16 + r] = acc[t][0][r] + acc[t][1][r];

    float u1[16];
    #pragma unroll
    for (int k = 0; k < 16; k++) {
        float snd = (l5 & 1) ? v[2 * k] : v[2 * k + 1];
        float got = __shfl_xor(snd, 1, 64);
        u1[k] = ((l5 & 1) ? v[2 * k + 1] : v[2 * k]) + got;
    }
    float u2[8];
    #pragma unroll
    for (int k = 0; k < 8; k++) {
        float snd = ((l5 >> 1) & 1) ? u1[2 * k] : u1[2 * k + 1];
        float got = __shfl_xor(snd, 2, 64);
        u2[k] = (((l5 >> 1) & 1) ? u1[2 * k + 1] : u1[2 * k]) + got;
    }
    float u3[4];
    #pragma unroll
    for (int k = 0; k < 4; k++) {
        float snd = ((l5 >> 2) & 1) ? u2[2 * k] : u2[2 * k + 1];
        float got = __shfl_xor(snd, 4, 64);
        u3[k] = (((l5 >> 2) & 1) ? u2[2 * k + 1] : u2[2 * k]) + got;
    }
    float u4[2];
    #pragma unroll
    for (int k = 0; k < 2; k++) {
        float snd = ((l5 >> 3) & 1) ? u3[2 * k] : u3[2 * k + 1];
        float got = __shfl_xor(snd, 8, 64);
        u4[k] = (((l5 >> 3) & 1) ? u3[2 * k + 1] : u3[2 * k]) + got;
    }
    {
        float snd = ((l5 >> 4) & 1) ? u4[0] : u4[1];
        float got = __shfl_xor(snd, 16, 64);
        float wr = (((l5 >> 4) & 1) ? u4[1] : u4[0]) + got;
        // lane l5 holds row-sum for t=l5: ti = l5>>4, reg = l5&15
        int reg = l5 & 15;
        int row = bi + wm * 64 + (l5 >> 4) * 32
                + (reg & 3) + 8 * (reg >> 2) + 4 * h;
        atomicAdd(&rs[row], wr);
    }

    // Col sums: c[tj] over both ti tiles' regs; reduce over h-halves.
    float c0 = 0.f, c1 = 0.f;
    #pragma unroll
    for (int t = 0; t < 2; t++)
        #pragma unroll
        for (int r = 0; r < 16; r++) {
            c0 += acc[t][0][r];
            c1 += acc[t][1][r];
        }
    {
        float snd = h ? c0 : c1;
        float got = __shfl_xor(snd, 32, 64);
        float cc = (h ? c1 : c0) + got;
        atomicAdd(&cs[bj + wn * 64 + h * 32 + l5], cc);
    }
}

// 64 blocks: each thread one (pair,row) entry; wave-reduce then atomicAdd
// into out (prep pre-set out = 40, the 20*4B/(2B) constant).
// log(r*c) replaces log r + log c: r,c in [e^-80*eps, 1.7e7] -- no overflow.
__global__ __launch_bounds__(256)
void final_reduce_kernel(const float* __restrict__ rowsum,
                         const float* __restrict__ colsum,
                         const float* __restrict__ diag,
                         float* __restrict__ out) {
    int idx = blockIdx.x * 256 + threadIdx.x;
    float acc = 0.5f * __logf(rowsum[idx] * colsum[idx]) - diag[idx];
    #pragma unroll
    for (int s = 32; s; s >>= 1) acc += __shfl_xor(acc, s, 64);
    if ((threadIdx.x & 63) == 0)
        atomicAdd(out, acc * (1.0f / (2.0f * BSZ)));
}

extern "C" void kernel_launch(void* const* d_in, const int* in_sizes, int n_in,
                              void* d_out, int out_size, void* d_ws, size_t ws_size,
                              hipStream_t stream) {
    const float* in_anchor = (const float*)d_in[0];
    const float* in_pos    = (const float*)d_in[1];
    // d_in[2] (reference_anchor) intentionally unused, matching the reference.
    const float* in_rtext  = (const float*)d_in[3];
    const float* in_rvis   = (const float*)d_in[4];

    char* ws = (char*)d_ws;
    unsigned char* f8 = (unsigned char*)ws;                 // 4 * B * D fp8
    size_t f8_bytes = (size_t)4 * BSZ * DIM;
    float* rowsum = (float*)(ws + f8_bytes);                // 4 * B
    float* colsum = rowsum + 4 * BSZ;                       // 4 * B
    float* diag   = colsum + 4 * BSZ;                       // 4 * B

    prep_kernel<<<BSZ / 4, 256, 0, stream>>>(
        in_anchor, in_pos, in_rtext, in_rvis, f8, diag, rowsum, colsum,
        (float*)d_out);

    pair_scores_kernel<<<dim3(BSZ / 128, BSZ / 128, 4), 256, 0, stream>>>(
        f8, rowsum, colsum);

    final_reduce_kernel<<<64, 256, 0, stream>>>(
        rowsum, colsum, diag, (float*)d_out);
}